// Round 8
// baseline (191.186 us; speedup 1.0000x reference)
//
#include <hip/hip_runtime.h>
#include <cstdint>

#define BB 2
#define NN 16384
#define MM 4096
#define CF 256
#define CT 128
#define CP 64

// ======================= kernel 1: 3-NN -> workspace =======================
// Round-8: R2's proven 70us kernel with ONE change: Q=2 queries per lane
// (16 sub-lanes/query, lane owns adjacent queries nA, nA+1). Each
// ds_read_b128 now feeds 2 distance computations -> LDS-pipe instructions
// halve (8192 -> 4096 per CU). Cross-config calibration (R2=70, R3=84.5,
// R4=92, R5=78) shows VALU ~22us/SIMD is config-invariant and the LDS pipe
// (~41us at R2's geometry) is the differentiator; R5 proved extra waves
// don't help (pipe saturated). Gate+tau kept EXACTLY (R4's regression was
// gate removal, not Q=2 -- Q=2 merge semantics validated bit-exact there).
// Bit-exactness: pre-doubled refs (fl(c*2r)=2fl(cr), fl(2a+2b)=2fl(a+b) at
// N(0,1) scales), numpy sum order, contract off; strict-< index network
// (ascending per-lane j streams, first-seen tie = lowest j); min/med3 exact
// value network; tau pruning drops only globally-dominated dd; lexicographic
// butterfly merge (stable top_k tie rule).
#define TPB1 512
#define NPB1 64
#define CHUNK 2048

__global__ __launch_bounds__(TPB1, 4) void knn_kernel(
    const float* __restrict__ coords,      // [B,N,3]
    const float* __restrict__ ref_coords,  // [B,M,3]
    int4* __restrict__ wsI,                // [B,N] {i0,i1,i2,-}
    float4* __restrict__ wsW)              // [B,N] {w0,w1,w2,-}
{
#pragma clang fp contract(off)
    __shared__ float4 refs[CHUNK];      // 32 KB (2x, 2y, 2z, rr)

    const int tid = threadIdx.x;
    const int b   = blockIdx.y;
    const int n0  = blockIdx.x * NPB1;

    const int pl = tid >> 4;            // query-pair group 0..31
    const int s  = tid & 15;            // sub-lane 0..15
    const int nA = n0 + pl * 2;         // this lane's queries: nA, nA+1

    const float* cp = coords + ((size_t)b * NN + nA) * 3;
    const float ax = cp[0], ay = cp[1], az = cp[2];
    const float bx = cp[3], by = cp[4], bz = cp[5];
    const float acc_ = (ax * ax + ay * ay) + az * az;   // numpy sum order
    const float bcc_ = (bx * bx + by * by) + bz * bz;

    float aD0 = INFINITY, aD1 = INFINITY, aD2 = INFINITY;
    float bD0 = INFINITY, bD1 = INFINITY, bD2 = INFINITY;
    int   aI0 = 0, aI1 = 0, aI2 = 0;
    int   bI0 = 0, bI1 = 0, bI2 = 0;
    float tauA = INFINITY, tauB = INFINITY;   // 16-lane pruning thresholds
    float thrA = INFINITY, thrB = INFINITY;   // min(own d2, tau)

    const float* rc = ref_coords + (size_t)b * MM * 3;

    for (int ch = 0; ch < MM / CHUNK; ++ch) {
        __syncthreads();                 // refs[] reuse guard
        for (int e = tid; e < CHUNK; e += TPB1) {
            const int j = ch * CHUNK + e;
            const float x = rc[3 * j + 0];
            const float y = rc[3 * j + 1];
            const float z = rc[3 * j + 2];
            // rr from ORIGINAL coords (numpy order); xyz pre-doubled (exact)
            refs[e] = make_float4(x + x, y + y, z + z, (x * x + y * y) + z * z);
        }
        __syncthreads();

        const int jbase = ch * CHUNK;
        // lane scans e = s + 16k ascending -> strict '<' keeps lowest idx;
        // tau refresh every 32 iterations (proven cadence)
        for (int it0 = 0; it0 < CHUNK / 16; it0 += 32) {
            #pragma unroll 4
            for (int k = 0; k < 32; ++k) {
                const int e = s + ((it0 + k) << 4);
                const float4 r = refs[e];
                // dot2 == 2*((cx*rx + cy*ry) + cz*rz) bit-exactly
                const float dotA = (ax * r.x + ay * r.y) + az * r.z;
                const float ddA  = (acc_ + r.w) - dotA;      // == numpy d2
                const float dotB = (bx * r.x + by * r.y) + bz * r.z;
                const float ddB  = (bcc_ + r.w) - dotB;
                // Wave-uniform skip: if no lane beats either threshold,
                // every dd is provably dead (>= own d2 no-op, or >= tau
                // globally dominated). Bodies are the ORIGINAL exact update.
                if (__any((ddA < thrA) || (ddB < thrB))) {
                    const int j = jbase + e;
                    {   // query A
                        const bool l2 = ddA < aD2;
                        const bool l1 = ddA < aD1;
                        const bool l0 = ddA < aD0;
                        aI2 = l2 ? (l1 ? aI1 : j) : aI2;
                        aI1 = l1 ? (l0 ? aI0 : j) : aI1;
                        aI0 = l0 ? j : aI0;
                        const float n2  = __builtin_amdgcn_fmed3f(ddA, aD1, aD2);
                        const float n1  = __builtin_amdgcn_fmed3f(ddA, aD0, aD1);
                        const float n0v = fminf(ddA, aD0);
                        aD2 = n2; aD1 = n1; aD0 = n0v;
                    }
                    {   // query B
                        const bool l2 = ddB < bD2;
                        const bool l1 = ddB < bD1;
                        const bool l0 = ddB < bD0;
                        bI2 = l2 ? (l1 ? bI1 : j) : bI2;
                        bI1 = l1 ? (l0 ? bI0 : j) : bI1;
                        bI0 = l0 ? j : bI0;
                        const float n2  = __builtin_amdgcn_fmed3f(ddB, bD1, bD2);
                        const float n1  = __builtin_amdgcn_fmed3f(ddB, bD0, bD1);
                        const float n0v = fminf(ddB, bD0);
                        bD2 = n2; bD1 = n1; bD0 = n0v;
                    }
                    thrA = fminf(aD2, tauA);
                    thrB = fminf(bD2, tauB);
                }
            }
            // refresh taus = min of the 16 sub-lanes' d2 (in-wave shfls)
            float tA = aD2, tB = bD2;
            tA = fminf(tA, __shfl_xor(tA, 1, 64));
            tB = fminf(tB, __shfl_xor(tB, 1, 64));
            tA = fminf(tA, __shfl_xor(tA, 2, 64));
            tB = fminf(tB, __shfl_xor(tB, 2, 64));
            tA = fminf(tA, __shfl_xor(tA, 4, 64));
            tB = fminf(tB, __shfl_xor(tB, 4, 64));
            tA = fminf(tA, __shfl_xor(tA, 8, 64));
            tB = fminf(tB, __shfl_xor(tB, 8, 64));
            tauA = tA;  tauB = tB;
            thrA = fminf(aD2, tauA);
            thrB = fminf(bD2, tauB);
        }
    }

    // lexicographic (d, idx) merge: lower index wins exact ties (stable
    // top_k). Butterfly across the 16 sub-lanes (xor<16 stays in-wave).
    for (int off = 1; off < 16; off <<= 1) {
        {
            const float e0 = __shfl_xor(aD0, off, 64);
            const float e1 = __shfl_xor(aD1, off, 64);
            const float e2 = __shfl_xor(aD2, off, 64);
            const int   f0 = __shfl_xor(aI0, off, 64);
            const int   f1 = __shfl_xor(aI1, off, 64);
            const int   f2 = __shfl_xor(aI2, off, 64);
            auto ins = [&](float e, int f) {
                const bool l2 = (e < aD2) || (e == aD2 && f < aI2);
                const bool l1 = (e < aD1) || (e == aD1 && f < aI1);
                const bool l0 = (e < aD0) || (e == aD0 && f < aI0);
                aD2 = l2 ? (l1 ? aD1 : e) : aD2;  aI2 = l2 ? (l1 ? aI1 : f) : aI2;
                aD1 = l1 ? (l0 ? aD0 : e) : aD1;  aI1 = l1 ? (l0 ? aI0 : f) : aI1;
                aD0 = l0 ? e : aD0;               aI0 = l0 ? f : aI0;
            };
            ins(e0, f0); ins(e1, f1); ins(e2, f2);
        }
        {
            const float e0 = __shfl_xor(bD0, off, 64);
            const float e1 = __shfl_xor(bD1, off, 64);
            const float e2 = __shfl_xor(bD2, off, 64);
            const int   f0 = __shfl_xor(bI0, off, 64);
            const int   f1 = __shfl_xor(bI1, off, 64);
            const int   f2 = __shfl_xor(bI2, off, 64);
            auto ins = [&](float e, int f) {
                const bool l2 = (e < bD2) || (e == bD2 && f < bI2);
                const bool l1 = (e < bD1) || (e == bD1 && f < bI1);
                const bool l0 = (e < bD0) || (e == bD0 && f < bI0);
                bD2 = l2 ? (l1 ? bD1 : e) : bD2;  bI2 = l2 ? (l1 ? bI1 : f) : bI2;
                bD1 = l1 ? (l0 ? bD0 : e) : bD1;  bI1 = l1 ? (l0 ? bI0 : f) : bI1;
                bD0 = l0 ? e : bD0;               bI0 = l0 ? f : bI0;
            };
            ins(e0, f0); ins(e1, f1); ins(e2, f2);
        }
    }

    if (s == 0) {
        {
            float w0 = 1.0f / (aD0 + 1e-8f);     // IEEE divs, numpy order
            float w1 = 1.0f / (aD1 + 1e-8f);
            float w2 = 1.0f / (aD2 + 1e-8f);
            const float sum = (w0 + w1) + w2;
            wsI[(size_t)b * NN + nA] = make_int4(aI0, aI1, aI2, 0);
            wsW[(size_t)b * NN + nA] = make_float4(w0 / sum, w1 / sum, w2 / sum, 0.0f);
        }
        {
            float w0 = 1.0f / (bD0 + 1e-8f);
            float w1 = 1.0f / (bD1 + 1e-8f);
            float w2 = 1.0f / (bD2 + 1e-8f);
            const float sum = (w0 + w1) + w2;
            wsI[(size_t)b * NN + nA + 1] = make_int4(bI0, bI1, bI2, 0);
            wsW[(size_t)b * NN + nA + 1] = make_float4(w0 / sum, w1 / sum, w2 / sum, 0.0f);
        }
    }
}

// ===================== kernel 2: row-staged interpolation ====================
// EXACT round-3 kernel — the measured-best interp (~24 us): 2 rows per block
// halves idx/w L2 re-reads; software-pipelined ws loads hide L2 latency;
// pf rows are pure float4 copies. Same fma ordering (contract off) ->
// bit-identical interpolation.
#define TPB2 512
#define NIB  (BB * (CF + CT) / 2)   // 384 interp blocks (2 rows each)
#define NCB  32                     // copy blocks (4 pf rows each)

__global__ __launch_bounds__(TPB2, 8) void interp_kernel(
    const float* __restrict__ refF,        // [B,256,M]
    const float* __restrict__ refT,        // [B,128,M]
    const float* __restrict__ pf,          // [B,64,N]
    const int4*  __restrict__ wsI,         // [B,N]
    const float4* __restrict__ wsW,        // [B,N]
    float* __restrict__ out)               // [B,320,N] ++ [B,128,N]
{
#pragma clang fp contract(off)
    __shared__ float rowA[MM];             // 16 KB
    __shared__ float rowB[MM];             // 16 KB
    const int tid  = threadIdx.x;
    const int task = blockIdx.x;
    const size_t outT_base = (size_t)BB * (CF + CP) * NN;

    if (task >= NIB) {                     // -------- pf copy blocks --------
        const int t3 = task - NIB;         // 0..31, 4 rows each
        for (int j = 0; j < 4; ++j) {
            const int r  = t3 * 4 + j;
            const int bb = r >> 6;
            const int c  = r & (CP - 1);
            const float4* s4 = (const float4*)(pf + ((size_t)bb * CP + c) * NN);
            float4* d4 = (float4*)(out + ((size_t)bb * (CF + CP) + CF + c) * NN);
            for (int i = tid; i < NN / 4; i += TPB2) d4[i] = s4[i];
        }
        return;                            // block-uniform exit
    }

    const int r0 = task * 2;               // rows r0, r0+1 (same b, same class)
    const float* src0;
    float* dst0;
    int b;
    if (r0 < BB * CF) {                    // interpolated features
        b = r0 >> 8;
        const int c = r0 & (CF - 1);
        src0 = refF + ((size_t)b * CF + c) * MM;
        dst0 = out + ((size_t)b * (CF + CP) + c) * NN;
    } else {                               // interpolated t_embed
        const int r2 = r0 - BB * CF;
        b = r2 >> 7;
        const int c = r2 & (CT - 1);
        src0 = refT + ((size_t)b * CT + c) * MM;
        dst0 = out + outT_base + ((size_t)b * CT + c) * NN;
    }
    const float* src1 = src0 + MM;
    float* dst1 = dst0 + NN;

    for (int i = tid; i < MM / 4; i += TPB2) {
        ((float4*)rowA)[i] = ((const float4*)src0)[i];
        ((float4*)rowB)[i] = ((const float4*)src1)[i];
    }
    __syncthreads();

    const int4*   wi = wsI + (size_t)b * NN;
    const float4* ww = wsW + (size_t)b * NN;

    auto clampi = [](int v) { return v < 0 ? 0 : (v > MM - 1 ? MM - 1 : v); };

    int4   id = wi[tid];
    float4 w  = ww[tid];
    for (int nq = tid; nq < NN; nq += TPB2) {
        const int nq2 = nq + TPB2;
        int4   idn;
        float4 wn;
        if (nq2 < NN) { idn = wi[nq2]; wn = ww[nq2]; }   // prefetch next
        const int a0 = clampi(id.x), a1 = clampi(id.y), a2 = clampi(id.z);
        dst0[nq] = (w.x * rowA[a0] + w.y * rowA[a1]) + w.z * rowA[a2];
        dst1[nq] = (w.x * rowB[a0] + w.y * rowB[a1]) + w.z * rowB[a2];
        id = idn; w = wn;
    }
}

extern "C" void kernel_launch(void* const* d_in, const int* in_sizes, int n_in,
                              void* d_out, int out_size, void* d_ws, size_t ws_size,
                              hipStream_t stream) {
    const float* coords     = (const float*)d_in[0];
    const float* ref_coords = (const float*)d_in[1];
    const float* refF       = (const float*)d_in[2];
    const float* refT       = (const float*)d_in[3];
    const float* pf         = (const float*)d_in[4];
    float* out = (float*)d_out;

    int4*   wsI = (int4*)d_ws;
    float4* wsW = (float4*)((char*)d_ws + (size_t)BB * NN * sizeof(int4));

    hipLaunchKernelGGL(knn_kernel, dim3(NN / NPB1, BB), dim3(TPB1), 0, stream,
                       coords, ref_coords, wsI, wsW);
    hipLaunchKernelGGL(interp_kernel, dim3(NIB + NCB), dim3(TPB2), 0, stream,
                       refF, refT, pf, wsI, wsW, out);
}